// Round 12
// baseline (524.454 us; speedup 1.0000x reference)
//
#include <hip/hip_runtime.h>
#include <hip/hip_bf16.h>

typedef __hip_bfloat16 bf16;
typedef __bf16 bf16r;
typedef bf16r bf16x8 __attribute__((ext_vector_type(8)));
typedef bf16r bf16x4 __attribute__((ext_vector_type(4)));
typedef float f32x4 __attribute__((ext_vector_type(4)));

#define T_SEQ 4096
#define C_DIM 1024
#define LD_QKV 3072
#define MB(x) ((size_t)(x) << 20)
// 0.125 (1/sqrt(64)) * log2(e): softmax runs in exp2 domain.  Folded into the
// Q-projection weights at cvt time, so QK^T lands already log2-scaled.
#define SCL 0.18033688011112042f

#define AS1 __attribute__((address_space(1)))
#define AS3 __attribute__((address_space(3)))

static __device__ __forceinline__ unsigned short f2bf(float f) {
    bf16 h = (bf16)f;
    return *reinterpret_cast<unsigned short*>(&h);
}

// ---------------------------------------------------------------------------
// Fused attention-weight convert: c_attn_w (first 786432 f4, Q rows scaled
// by SCL) and c_proj_w (262144 f4) -> one contiguous bf16 dst (cwA||cwP).
// ---------------------------------------------------------------------------
__global__ __launch_bounds__(256) void cvt_attn(const float* __restrict__ srcA,
                                                const float* __restrict__ srcP,
                                                ushort4* __restrict__ dst) {
    int i = blockIdx.x * 256 + threadIdx.x;
    const int stride = gridDim.x * 256;
    for (; i < 1048576; i += stride) {
        const bool isA = i < 786432;
        float4 v = isA ? ((const float4*)srcA)[i] : ((const float4*)srcP)[i - 786432];
        const float m = (i < 262144) ? SCL : 1.0f;
        ushort4 o;
        o.x = f2bf(v.x * m); o.y = f2bf(v.y * m); o.z = f2bf(v.z * m); o.w = f2bf(v.w * m);
        dst[i] = o;
    }
}

// ---------------------------------------------------------------------------
// f32 -> bf16 weight convert, contiguous slice.
// ---------------------------------------------------------------------------
__global__ __launch_bounds__(256) void cvt_w(const float* __restrict__ src, size_t eoff,
                                             ushort4* __restrict__ dst, int n4) {
    int i = blockIdx.x * 256 + threadIdx.x;
    const int stride = gridDim.x * 256;
    const float4* s = (const float4*)(src + eoff);
    for (; i < n4; i += stride) {
        float4 v = s[i];
        ushort4 o;
        o.x = f2bf(v.x); o.y = f2bf(v.y); o.z = f2bf(v.z); o.w = f2bf(v.w);
        dst[i] = o;
    }
}

// ---------------------------------------------------------------------------
// fused w1 + w3 convert (same [4096][1024] shape): one launch, two streams
// ---------------------------------------------------------------------------
__global__ __launch_bounds__(256) void cvt_w13(const float* __restrict__ s1,
                                               const float* __restrict__ s3,
                                               ushort4* __restrict__ d1,
                                               ushort4* __restrict__ d3, int n4) {
    int i = blockIdx.x * 256 + threadIdx.x;
    const int stride = gridDim.x * 256;
    for (; i < n4; i += stride) {
        float4 v1 = ((const float4*)s1)[i];
        float4 v3 = ((const float4*)s3)[i];
        ushort4 o1, o3;
        o1.x = f2bf(v1.x); o1.y = f2bf(v1.y); o1.z = f2bf(v1.z); o1.w = f2bf(v1.w);
        o3.x = f2bf(v3.x); o3.y = f2bf(v3.y); o3.z = f2bf(v3.z); o3.w = f2bf(v3.w);
        d1[i] = o1;
        d3[i] = o3;
    }
}

// ---------------------------------------------------------------------------
// f32 grid-stride copy (xmid = x prefill for the atomic split-K epilogues)
// ---------------------------------------------------------------------------
__global__ __launch_bounds__(256) void copy_f32(const float4* __restrict__ src,
                                                float4* __restrict__ dst, int n4) {
    int i = blockIdx.x * 256 + threadIdx.x;
    const int stride = gridDim.x * 256;
    for (; i < n4; i += stride) dst[i] = src[i];
}

// ---------------------------------------------------------------------------
// RMSNorm: f32 in, f32 weight, bf16 out. One block per row of 1024.
// ---------------------------------------------------------------------------
__global__ __launch_bounds__(256) void rmsnorm_k(const float* __restrict__ x,
                                                 const float* __restrict__ w,
                                                 bf16* __restrict__ out) {
    const int row = blockIdx.x;
    const int tid = threadIdx.x;
    const float* xr = x + (size_t)row * C_DIM;
    float v[4];
    float ss = 0.f;
#pragma unroll
    for (int i = 0; i < 4; i++) { v[i] = xr[tid * 4 + i]; ss += v[i] * v[i]; }
#pragma unroll
    for (int off = 32; off; off >>= 1) ss += __shfl_xor(ss, off);
    __shared__ float red[4];
    if ((tid & 63) == 0) red[tid >> 6] = ss;
    __syncthreads();
    const float tot = red[0] + red[1] + red[2] + red[3];
    const float scale = rsqrtf(tot * (1.0f / C_DIM) + 1e-6f);
#pragma unroll
    for (int i = 0; i < 4; i++) {
        const int c = tid * 4 + i;
        out[(size_t)row * C_DIM + c] = (bf16)(v[i] * scale * w[c]);
    }
}

// ---------------------------------------------------------------------------
// m97-structure GEMM, BK=64.  K is PER-SLICE; blockIdx.z selects the K-slice
// (split-K).  Epilogues: RESID==2 f32 resid add; RESID==3 silu(resid)*acc
// (resid bf16, may alias out -- per-thread read-then-write, race-free);
// RESID==4 f32 atomicAdd (out prefilled).
// Round 12: w13 is UNFUSED into two gemm128 passes -- the dual-acc gemm_w13
// (128 acc VGPRs + launch_bounds(256,2)) was capped at 2 blocks/CU, running
// its 1024-block grid in two dispatch rounds; single-acc gemm128 (~120 VGPR,
// 32 KB LDS) sustains 4 blocks/CU -> fully-resident grid.
// ---------------------------------------------------------------------------
template <int RESID, int OUTF32>
__global__ __launch_bounds__(256) void gemm128(const bf16* __restrict__ A, int lda,
                                               const bf16* __restrict__ B, int ldb,
                                               const void* __restrict__ resid,
                                               void* __restrict__ out,
                                               int N, int K) {
    __shared__ __align__(16) bf16r As[128 * 64];
    __shared__ __align__(16) bf16r Bs[128 * 64];
    const int tid = threadIdx.x;
    const int w = tid >> 6, lane = tid & 63;
    const int c = lane & 15, qd = lane >> 4;
    const int wm = w >> 1, wn = w & 1;
    const int mbase = blockIdx.y * 128;
    const int nbase = blockIdx.x * 128;
    const size_t koff = (size_t)blockIdx.z * K;

    const int srow = lane >> 3, schk = lane & 7;  // 8 rows x 8 chunks of 8
    const bf16* gA = A + (size_t)(mbase + srow) * lda + schk * 8 + koff;
    const bf16* gB = B + (size_t)(nbase + srow) * ldb + schk * 8 + koff;

    f32x4 acc[4][4] = {};

    for (int k0 = 0; k0 < K; k0 += 64) {
        __syncthreads();
#pragma unroll
        for (int g = 0; g < 4; g++) {
            const int grp = w * 4 + g;            // 0..15 -> rows grp*8..+7
            __builtin_amdgcn_global_load_lds(
                (const AS1 void*)(gA + (size_t)(grp * 8) * lda + k0),
                (AS3 void*)&As[grp * 8 * 64], 16, 0, 0);
            __builtin_amdgcn_global_load_lds(
                (const AS1 void*)(gB + (size_t)(grp * 8) * ldb + k0),
                (AS3 void*)&Bs[grp * 8 * 64], 16, 0, 0);
        }
        __syncthreads();

#pragma unroll
        for (int kk = 0; kk < 2; kk++) {
            bf16x8 a[4], b[4];
#pragma unroll
            for (int i = 0; i < 4; i++)
                a[i] = *(const bf16x8*)&As[(wm * 64 + i * 16 + c) * 64 + kk * 32 + qd * 8];
#pragma unroll
            for (int j = 0; j < 4; j++)
                b[j] = *(const bf16x8*)&Bs[(wn * 64 + j * 16 + c) * 64 + kk * 32 + qd * 8];
#pragma unroll
            for (int i = 0; i < 4; i++)
#pragma unroll
                for (int j = 0; j < 4; j++)
                    acc[i][j] = __builtin_amdgcn_mfma_f32_16x16x32_bf16(a[i], b[j], acc[i][j], 0, 0, 0);
        }
    }

#pragma unroll
    for (int i = 0; i < 4; i++) {
#pragma unroll
        for (int j = 0; j < 4; j++) {
            const int col = nbase + wn * 64 + j * 16 + c;
#pragma unroll
            for (int reg = 0; reg < 4; reg++) {
                const int row = mbase + wm * 64 + i * 16 + qd * 4 + reg;
                const size_t idx = (size_t)row * N + col;
                float v = acc[i][j][reg];
                if (RESID == 2) v += ((const float*)resid)[idx];
                if (RESID == 3) {
                    const float a1 = (float)((const bf16*)resid)[idx];
                    v = (a1 / (1.0f + __expf(-a1))) * v;
                }
                if (RESID == 4) {
                    atomicAdd(&((float*)out)[idx], v);
                } else if (OUTF32) {
                    ((float*)out)[idx] = v;
                } else {
                    ((bf16*)out)[idx] = (bf16)v;
                }
            }
        }
    }
}

// ---------------------------------------------------------------------------
// Transpose a qkv section to [h][d][t].  Block (0,0) also zeroes the attn
// work-queue counters (fused zero_ctr).
// ---------------------------------------------------------------------------
#define CTR_STRIDE 16  // ints; 64 B per counter line
__global__ __launch_bounds__(256) void build_tr(const bf16* __restrict__ qkv,
                                                bf16* __restrict__ dst, int soff,
                                                int* __restrict__ ctrs) {
    if (blockIdx.x == 0 && blockIdx.y == 0 && threadIdx.x < 8 * CTR_STRIDE)
        ctrs[threadIdx.x] = 0;
    const int h = blockIdx.y;
    const int tb = blockIdx.x;
    __shared__ bf16 tile[64][65];
    const int tx = threadIdx.x & 63;
    const int ty = threadIdx.x >> 6;
    for (int rr = ty; rr < 64; rr += 4)
        tile[rr][tx] = qkv[(size_t)(tb * 64 + rr) * LD_QKV + soff + h * 64 + tx];
    __syncthreads();
    for (int rr = ty; rr < 64; rr += 4)
        dst[((size_t)h * 64 + rr) * T_SEQ + tb * 64 + tx] = tile[tx][rr];
}

// ---------------------------------------------------------------------------
// MFMA flash attention — round-8 body, verbatim (measured 100.7-101.5 us
// across four rounds).  Persistent blocks + 8 LPT work queues (whole tiles,
// qb descending) + scale-folded exp2 softmax + defer-max + serial
// reg-staging (reg 100.7 < gload_lds 117.4 < dbuf 151 us).
// ---------------------------------------------------------------------------
__global__ __launch_bounds__(256) void attn_mfma(const bf16* __restrict__ qkv,
                                                 const bf16* __restrict__ VT,
                                                 bf16* __restrict__ y,
                                                 int* __restrict__ ctrs) {
    __shared__ __align__(16) bf16r Ks[128][64];    // keys x d
    __shared__ __align__(16) bf16r VTs[64][128];   // d x keys
    __shared__ __align__(16) bf16r Ps[4][16][128]; // per-wave q x keys
    __shared__ int s_wi;

    const int tid  = threadIdx.x;
    const int w    = tid >> 6;
    const int lane = tid & 63;
    const int c    = lane & 15;
    const int qd   = lane >> 4;
    const int sw   = c & 7;            // xor swizzle key for frag reads
    const int qi   = blockIdx.x & 7;   // queue = presumed XCD
    int* ctr = ctrs + qi * CTR_STRIDE;

    while (true) {
        __syncthreads();               // LDS + s_wi safe to reuse
        if (tid == 0) s_wi = atomicAdd(ctr, 1);
        __syncthreads();
        const int j = s_wi;
        if (j >= 128) break;           // queue drained (uniform exit)

        const int h    = qi + 8 * (j & 1);      // heads {qi, qi+8}
        const int qb   = 63 - (j >> 1);         // largest-first (LPT)
        const int qrow = qb * 64 + w * 16 + c;

        // Q B-frags: lane holds Q[qrow][ks*32 + qd*8 + jj]  (pre-scaled by SCL)
        bf16x8 qf[2];
        {
            const bf16* qp = qkv + (size_t)qrow * LD_QKV + h * 64;
            qf[0] = *(const bf16x8*)(qp + qd * 8);
            qf[1] = *(const bf16x8*)(qp + 32 + qd * 8);
        }

        f32x4 O[4] = {};               // O^T: D[row=d=dt*16+qd*4+r][col=q=c]
        float m_i = -1e30f, l_i = 0.f; // m_i in log2 domain
        const int nkb = (qb >> 1) + 1; // 128-key chunks

        for (int kb = 0; kb < nkb; kb++) {
            __syncthreads();           // prior iteration's LDS reads done
#pragma unroll
            for (int ii = 0; ii < 4; ii++) {
                const int i = ii * 256 + tid;
                const int kr = i >> 3, ch = i & 7;    // K: 128 rows x 8 chunks
                *(bf16x8*)&Ks[kr][(ch ^ (kr & 7)) * 8] =
                    *(const bf16x8*)(qkv + (size_t)(kb * 128 + kr) * LD_QKV + C_DIM + h * 64 + ch * 8);
                const int vr = i >> 4, vch = i & 15;  // VT: 64 rows x 16 chunks
                *(bf16x8*)&VTs[vr][(vch ^ (vr & 7)) * 8] =
                    *(const bf16x8*)(VT + ((size_t)h * 64 + vr) * T_SEQ + kb * 128 + vch * 8);
            }
            __syncthreads();

            // ---- S^T = K Q^T : rows = keys (kt*16+qd*4+r), cols = q (c) ----
            f32x4 ST[8];
#pragma unroll
            for (int kt = 0; kt < 8; kt++) {
                f32x4 z = {};
#pragma unroll
                for (int ks = 0; ks < 2; ks++) {
                    bf16x8 kf = *(const bf16x8*)&Ks[kt * 16 + c][((ks * 4 + qd) ^ sw) * 8];
                    z = __builtin_amdgcn_mfma_f32_16x16x32_bf16(kf, qf[ks], z, 0, 0, 0);
                }
                ST[kt] = z;
            }

            // ---- causal mask on the diagonal chunk only ----
            if (kb == nkb - 1) {
#pragma unroll
                for (int kt = 0; kt < 8; kt++)
#pragma unroll
                    for (int r = 0; r < 4; r++)
                        if (kb * 128 + kt * 16 + qd * 4 + r > qrow) ST[kt][r] = -1e30f;
            }

            // ---- online softmax (exp2 domain), per-lane scalar stats ----
            float mb = -1e30f;
#pragma unroll
            for (int kt = 0; kt < 8; kt++)
#pragma unroll
                for (int r = 0; r < 4; r++) mb = fmaxf(mb, ST[kt][r]);
            mb = fmaxf(mb, __shfl_xor(mb, 16));
            mb = fmaxf(mb, __shfl_xor(mb, 32));

            bf16x4 pv[8];
            float rs = 0.f;
            if (__all(mb - m_i <= 8.0f)) {
                // defer-max: keep m_i, skip alpha-rescale; P bounded by 2^8
#pragma unroll
                for (int kt = 0; kt < 8; kt++)
#pragma unroll
                    for (int r = 0; r < 4; r++) {
                        const float p = exp2f(ST[kt][r] - m_i);
                        pv[kt][r] = (bf16r)p;
                        rs += p;
                    }
                rs += __shfl_xor(rs, 16);
                rs += __shfl_xor(rs, 32);
                l_i += rs;
            } else {
                const float mnew = fmaxf(m_i, mb);
                const float alpha = exp2f(m_i - mnew);
#pragma unroll
                for (int kt = 0; kt < 8; kt++)
#pragma unroll
                    for (int r = 0; r < 4; r++) {
                        const float p = exp2f(ST[kt][r] - mnew);
                        pv[kt][r] = (bf16r)p;
                        rs += p;
                    }
                rs += __shfl_xor(rs, 16);
                rs += __shfl_xor(rs, 32);
                l_i = l_i * alpha + rs;
                m_i = mnew;
#pragma unroll
                for (int dt = 0; dt < 4; dt++)
#pragma unroll
                    for (int r = 0; r < 4; r++) O[dt][r] *= alpha;
            }

            // ---- P^T -> Ps[q][key] via 8B vector writes (wave-private) ----
#pragma unroll
            for (int kt = 0; kt < 8; kt++) {
                const int phys = (kt * 2 + (qd >> 1)) ^ sw;  // 16B-chunk swizzle
                *(bf16x4*)&Ps[w][c][phys * 8 + (qd & 1) * 4] = pv[kt];
            }

            // ---- O^T += VT P^T (16x16x32) ----
#pragma unroll
            for (int ks = 0; ks < 4; ks++) {
                bf16x8 pf = *(const bf16x8*)&Ps[w][c][((ks * 4 + qd) ^ sw) * 8];
#pragma unroll
                for (int dt = 0; dt < 4; dt++) {
                    bf16x8 vf = *(const bf16x8*)&VTs[dt * 16 + c][((ks * 4 + qd) ^ sw) * 8];
                    O[dt] = __builtin_amdgcn_mfma_f32_16x16x32_bf16(vf, pf, O[dt], 0, 0, 0);
                }
            }
        }

        // ---- epilogue: y[qrow][h*64 + d], 8B vector stores ----
        const float inv_l = 1.0f / l_i;
#pragma unroll
        for (int dt = 0; dt < 4; dt++) {
            bf16x4 ov;
#pragma unroll
            for (int r = 0; r < 4; r++) ov[r] = (bf16r)(O[dt][r] * inv_l);
            *(bf16x4*)(y + (size_t)qrow * C_DIM + h * 64 + dt * 16 + qd * 4) = ov;
        }
    }
}

// ---------------------------------------------------------------------------
// launch.  Inputs f32, output f32.  ws peak = 56 MiB.
//
// Region timeline (stream-ordered, audited):
//   0..6   cwA  -> dead after qkv gemm -> rms2 [0..8] after proj
//   6..8   cwP  (live until proj)
//   8..16  rms1/ctrs -> W1 after attn -> W2 after w13
//   16..40 qkv -> W3 [16..24] + h1 tail after attn
//   40..48 VT  -> h1 ; 48..56 y -> h1 after proj
//   24..56 h1 [4096][4096] bf16; w1-gemm writes it, w3-gemm reads it as the
//   silu argument and overwrites in place (per-thread read-then-write).
// ---------------------------------------------------------------------------
extern "C" void kernel_launch(void* const* d_in, const int* in_sizes, int n_in,
                              void* d_out, int out_size, void* d_ws, size_t ws_size,
                              hipStream_t stream) {
    const float* x        = (const float*)d_in[0];
    const float* attn_w   = (const float*)d_in[1];
    const float* ffn_w    = (const float*)d_in[2];
    const float* c_attn_w = (const float*)d_in[3];
    const float* c_proj_w = (const float*)d_in[4];
    const float* w1       = (const float*)d_in[5];
    const float* w2       = (const float*)d_in[6];
    const float* w3       = (const float*)d_in[7];
    float* xmid = (float*)d_out;

    char* ws = (char*)d_ws;
    bf16* cwA  = (bf16*)(ws);            // 0..6   (cwA||cwP contiguous)
    bf16* cwP  = (bf16*)(ws + MB(6));    // 6..8
    bf16* rms1 = (bf16*)(ws + MB(8));    // 8..16
    bf16* qkv  = (bf16*)(ws + MB(16));   // 16..40
    bf16* VT   = (bf16*)(ws + MB(40));   // 40..48
    bf16* y    = (bf16*)(ws + MB(48));   // 48..56
    int*  ctrs = (int*)(ws + MB(8));     // over rms1 (dead after qkv gemm)
    bf16* rms2 = (bf16*)(ws);            // 0..8 (over cwA/cwP, after proj)
    bf16* w1h  = (bf16*)(ws + MB(8));    // 8..16 (over rms1/ctrs, after attn)
    bf16* w3h  = (bf16*)(ws + MB(16));   // 16..24 (over qkv, after attn)
    bf16* w2h  = (bf16*)(ws + MB(8));    // 8..16 (over w1h, after w1/w3 gemms)
    bf16* h1   = (bf16*)(ws + MB(24));   // 24..56 (over qkv tail/VT/y)

    // 1. attention weights -> bf16 (fused; Q-proj rows x SCL)
    cvt_attn<<<512, 256, 0, stream>>>(c_attn_w, c_proj_w, (ushort4*)cwA);
    // 2. rms1 = rmsnorm(x, attn_norm_w)
    rmsnorm_k<<<T_SEQ, 256, 0, stream>>>(x, attn_w, rms1);
    // 3. qkv = rms1 @ c_attn^T   [4096, 3072]
    gemm128<0, 0><<<dim3(24, 32), 256, 0, stream>>>(rms1, C_DIM, cwA, C_DIM, nullptr, qkv, 3072, 1024);
    // 4. VT (+ ctr zero) + persistent-block flash attention
    build_tr<<<dim3(64, 16), 256, 0, stream>>>(qkv, VT, 2 * C_DIM, ctrs);
    attn_mfma<<<768, 256, 0, stream>>>(qkv, VT, y, ctrs);
    // 5. FFN weight converts (regions dead after attn), xmid = x prefill
    cvt_w13<<<512, 256, 0, stream>>>(w1, w3, (ushort4*)w1h, (ushort4*)w3h, 4096 * 1024 / 4);
    copy_f32<<<2048, 256, 0, stream>>>((const float4*)x, (float4*)xmid, T_SEQ * C_DIM / 4);
    // 6. xmid += y @ c_proj^T   (split-K=2 atomic; 512 blocks = 2/CU)
    gemm128<4, 1><<<dim3(8, 32, 2), 256, 0, stream>>>(y, C_DIM, cwP, C_DIM, nullptr, xmid, 1024, 512);
    // 7. rms2 = rmsnorm(xmid, ffn_norm_w)   (into 0..8, cwA/cwP dead)
    rmsnorm_k<<<T_SEQ, 256, 0, stream>>>(xmid, ffn_w, rms2);
    // 8. FFN up-projections, unfused for full residency (1024 blocks, 4/CU):
    //    h1 = rms2 @ w1^T, then h1 = silu(h1) * (rms2 @ w3^T) in place.
    gemm128<0, 0><<<dim3(32, 32), 256, 0, stream>>>(rms2, C_DIM, w1h, C_DIM, nullptr, h1, 4096, 1024);
    gemm128<3, 0><<<dim3(32, 32), 256, 0, stream>>>(rms2, C_DIM, w3h, C_DIM, h1, h1, 4096, 1024);
    // 9. xmid += h1 @ w2^T   (full K=4096, split-K=4 atomic; 1024 blocks)
    cvt_w<<<512, 256, 0, stream>>>(w2, 0, (ushort4*)w2h, 1024 * 4096 / 4);
    gemm128<4, 1><<<dim3(8, 32, 4), 256, 0, stream>>>(h1, 4096, w2h, 4096, nullptr, xmid, 1024, 1024);
}

// Round 13
// 471.266 us; speedup vs baseline: 1.1129x; 1.1129x over previous
//
#include <hip/hip_runtime.h>
#include <hip/hip_bf16.h>

typedef __hip_bfloat16 bf16;
typedef __bf16 bf16r;
typedef bf16r bf16x8 __attribute__((ext_vector_type(8)));
typedef bf16r bf16x4 __attribute__((ext_vector_type(4)));
typedef float f32x4 __attribute__((ext_vector_type(4)));

#define T_SEQ 4096
#define C_DIM 1024
#define LD_QKV 3072
#define MB(x) ((size_t)(x) << 20)
// 0.125 (1/sqrt(64)) * log2(e): softmax runs in exp2 domain.  Folded into the
// Q-projection weights at cvt time, so QK^T lands already log2-scaled.
#define SCL 0.18033688011112042f

#define AS1 __attribute__((address_space(1)))
#define AS3 __attribute__((address_space(3)))

static __device__ __forceinline__ unsigned short f2bf(float f) {
    bf16 h = (bf16)f;
    return *reinterpret_cast<unsigned short*>(&h);
}

// ---------------------------------------------------------------------------
// Fused attention-weight convert: c_attn_w (first 786432 f4, Q rows scaled
// by SCL) and c_proj_w (262144 f4) -> one contiguous bf16 dst (cwA||cwP).
// ---------------------------------------------------------------------------
__global__ __launch_bounds__(256) void cvt_attn(const float* __restrict__ srcA,
                                                const float* __restrict__ srcP,
                                                ushort4* __restrict__ dst) {
    int i = blockIdx.x * 256 + threadIdx.x;
    const int stride = gridDim.x * 256;
    for (; i < 1048576; i += stride) {
        const bool isA = i < 786432;
        float4 v = isA ? ((const float4*)srcA)[i] : ((const float4*)srcP)[i - 786432];
        const float m = (i < 262144) ? SCL : 1.0f;
        ushort4 o;
        o.x = f2bf(v.x * m); o.y = f2bf(v.y * m); o.z = f2bf(v.z * m); o.w = f2bf(v.w * m);
        dst[i] = o;
    }
}

// ---------------------------------------------------------------------------
// f32 -> bf16 weight convert, contiguous slice.
// ---------------------------------------------------------------------------
__global__ __launch_bounds__(256) void cvt_w(const float* __restrict__ src, size_t eoff,
                                             ushort4* __restrict__ dst, int n4) {
    int i = blockIdx.x * 256 + threadIdx.x;
    const int stride = gridDim.x * 256;
    const float4* s = (const float4*)(src + eoff);
    for (; i < n4; i += stride) {
        float4 v = s[i];
        ushort4 o;
        o.x = f2bf(v.x); o.y = f2bf(v.y); o.z = f2bf(v.z); o.w = f2bf(v.w);
        dst[i] = o;
    }
}

// ---------------------------------------------------------------------------
// fused w1 + w3 convert (same [4096][1024] shape): one launch, two streams
// ---------------------------------------------------------------------------
__global__ __launch_bounds__(256) void cvt_w13(const float* __restrict__ s1,
                                               const float* __restrict__ s3,
                                               ushort4* __restrict__ d1,
                                               ushort4* __restrict__ d3, int n4) {
    int i = blockIdx.x * 256 + threadIdx.x;
    const int stride = gridDim.x * 256;
    for (; i < n4; i += stride) {
        float4 v1 = ((const float4*)s1)[i];
        float4 v3 = ((const float4*)s3)[i];
        ushort4 o1, o3;
        o1.x = f2bf(v1.x); o1.y = f2bf(v1.y); o1.z = f2bf(v1.z); o1.w = f2bf(v1.w);
        o3.x = f2bf(v3.x); o3.y = f2bf(v3.y); o3.z = f2bf(v3.z); o3.w = f2bf(v3.w);
        d1[i] = o1;
        d3[i] = o3;
    }
}

// ---------------------------------------------------------------------------
// RMSNorm: f32 in, f32 weight, bf16 out. One block per row of 1024.
// ---------------------------------------------------------------------------
__global__ __launch_bounds__(256) void rmsnorm_k(const float* __restrict__ x,
                                                 const float* __restrict__ w,
                                                 bf16* __restrict__ out) {
    const int row = blockIdx.x;
    const int tid = threadIdx.x;
    const float* xr = x + (size_t)row * C_DIM;
    float v[4];
    float ss = 0.f;
#pragma unroll
    for (int i = 0; i < 4; i++) { v[i] = xr[tid * 4 + i]; ss += v[i] * v[i]; }
#pragma unroll
    for (int off = 32; off; off >>= 1) ss += __shfl_xor(ss, off);
    __shared__ float red[4];
    if ((tid & 63) == 0) red[tid >> 6] = ss;
    __syncthreads();
    const float tot = red[0] + red[1] + red[2] + red[3];
    const float scale = rsqrtf(tot * (1.0f / C_DIM) + 1e-6f);
#pragma unroll
    for (int i = 0; i < 4; i++) {
        const int c = tid * 4 + i;
        out[(size_t)row * C_DIM + c] = (bf16)(v[i] * scale * w[c]);
    }
}

// ---------------------------------------------------------------------------
// Fused residual-join RMSNorm (round 13): t = x + p0 + p1 (the two proj
// split-K partials), writes xmid = t (f32, prefill for the w2 atomics AND
// the final residual base) and out = rmsnorm(t) * w (bf16).  Replaces the
// copy_f32 prefill + proj atomicAdd RMW path with plain stores + one pass.
// ---------------------------------------------------------------------------
__global__ __launch_bounds__(256) void rmsnorm_res(const float* __restrict__ x,
                                                   const float* __restrict__ p0,
                                                   const float* __restrict__ p1,
                                                   const float* __restrict__ w,
                                                   float* __restrict__ xmid,
                                                   bf16* __restrict__ out) {
    const int row = blockIdx.x;
    const int tid = threadIdx.x;
    const size_t base = (size_t)row * C_DIM + tid * 4;
    float4 a = *(const float4*)(x + base);
    float4 b = *(const float4*)(p0 + base);
    float4 d = *(const float4*)(p1 + base);
    float v[4] = {a.x + b.x + d.x, a.y + b.y + d.y, a.z + b.z + d.z, a.w + b.w + d.w};
    *(float4*)(xmid + base) = make_float4(v[0], v[1], v[2], v[3]);
    float ss = v[0] * v[0] + v[1] * v[1] + v[2] * v[2] + v[3] * v[3];
#pragma unroll
    for (int off = 32; off; off >>= 1) ss += __shfl_xor(ss, off);
    __shared__ float red[4];
    if ((tid & 63) == 0) red[tid >> 6] = ss;
    __syncthreads();
    const float tot = red[0] + red[1] + red[2] + red[3];
    const float scale = rsqrtf(tot * (1.0f / C_DIM) + 1e-6f);
#pragma unroll
    for (int i = 0; i < 4; i++)
        out[base + i] = (bf16)(v[i] * scale * w[tid * 4 + i]);
}

// ---------------------------------------------------------------------------
// m97-structure GEMM, BK=64.  K is PER-SLICE; blockIdx.z selects the K-slice
// (split-K).  Epilogues: RESID==2 f32 resid add; RESID==3 silu(resid)*acc;
// RESID==4 f32 atomicAdd (out prefilled); RESID==5 per-slice f32 partial
// store at out + z*4096*1024 (M=4096, N=1024 shapes only).
// ---------------------------------------------------------------------------
template <int RESID, int OUTF32>
__global__ __launch_bounds__(256) void gemm128(const bf16* __restrict__ A, int lda,
                                               const bf16* __restrict__ B, int ldb,
                                               const void* __restrict__ resid,
                                               void* __restrict__ out,
                                               int N, int K) {
    __shared__ __align__(16) bf16r As[128 * 64];
    __shared__ __align__(16) bf16r Bs[128 * 64];
    const int tid = threadIdx.x;
    const int w = tid >> 6, lane = tid & 63;
    const int c = lane & 15, qd = lane >> 4;
    const int wm = w >> 1, wn = w & 1;
    const int mbase = blockIdx.y * 128;
    const int nbase = blockIdx.x * 128;
    const size_t koff = (size_t)blockIdx.z * K;

    const int srow = lane >> 3, schk = lane & 7;  // 8 rows x 8 chunks of 8
    const bf16* gA = A + (size_t)(mbase + srow) * lda + schk * 8 + koff;
    const bf16* gB = B + (size_t)(nbase + srow) * ldb + schk * 8 + koff;

    f32x4 acc[4][4] = {};

    for (int k0 = 0; k0 < K; k0 += 64) {
        __syncthreads();
#pragma unroll
        for (int g = 0; g < 4; g++) {
            const int grp = w * 4 + g;            // 0..15 -> rows grp*8..+7
            __builtin_amdgcn_global_load_lds(
                (const AS1 void*)(gA + (size_t)(grp * 8) * lda + k0),
                (AS3 void*)&As[grp * 8 * 64], 16, 0, 0);
            __builtin_amdgcn_global_load_lds(
                (const AS1 void*)(gB + (size_t)(grp * 8) * ldb + k0),
                (AS3 void*)&Bs[grp * 8 * 64], 16, 0, 0);
        }
        __syncthreads();

#pragma unroll
        for (int kk = 0; kk < 2; kk++) {
            bf16x8 a[4], b[4];
#pragma unroll
            for (int i = 0; i < 4; i++)
                a[i] = *(const bf16x8*)&As[(wm * 64 + i * 16 + c) * 64 + kk * 32 + qd * 8];
#pragma unroll
            for (int j = 0; j < 4; j++)
                b[j] = *(const bf16x8*)&Bs[(wn * 64 + j * 16 + c) * 64 + kk * 32 + qd * 8];
#pragma unroll
            for (int i = 0; i < 4; i++)
#pragma unroll
                for (int j = 0; j < 4; j++)
                    acc[i][j] = __builtin_amdgcn_mfma_f32_16x16x32_bf16(a[i], b[j], acc[i][j], 0, 0, 0);
        }
    }

#pragma unroll
    for (int i = 0; i < 4; i++) {
#pragma unroll
        for (int j = 0; j < 4; j++) {
            const int col = nbase + wn * 64 + j * 16 + c;
#pragma unroll
            for (int reg = 0; reg < 4; reg++) {
                const int row = mbase + wm * 64 + i * 16 + qd * 4 + reg;
                const size_t idx = (size_t)row * N + col;
                float v = acc[i][j][reg];
                if (RESID == 2) v += ((const float*)resid)[idx];
                if (RESID == 3) {
                    const float a1 = (float)((const bf16*)resid)[idx];
                    v = (a1 / (1.0f + __expf(-a1))) * v;
                }
                if (RESID == 4) {
                    atomicAdd(&((float*)out)[idx], v);
                } else if (RESID == 5) {
                    ((float*)out)[(size_t)blockIdx.z * (4096 * 1024) + idx] = v;
                } else if (OUTF32) {
                    ((float*)out)[idx] = v;
                } else {
                    ((bf16*)out)[idx] = (bf16)v;
                }
            }
        }
    }
}

// ---------------------------------------------------------------------------
// Merged w1/w3 GEMM, BK=64: h = silu(A@B1^T) * (A@B3^T), bf16 out [M, N].
// Fused dual-acc version (R11): one A-staging feeds both B's.  Measured
// FASTER than two single-acc passes (R12: unfuse cost +39 us -- the shared
// A-staging beats the residency gain).
// ---------------------------------------------------------------------------
__global__ __launch_bounds__(256, 2) void gemm_w13(const bf16* __restrict__ A,
                                                   const bf16* __restrict__ B1,
                                                   const bf16* __restrict__ B3,
                                                   bf16* __restrict__ out,
                                                   int N, int K) {
    __shared__ __align__(16) bf16r As[128 * 64];
    __shared__ __align__(16) bf16r B1s[128 * 64];
    __shared__ __align__(16) bf16r B3s[128 * 64];
    const int tid = threadIdx.x;
    const int w = tid >> 6, lane = tid & 63;
    const int c = lane & 15, qd = lane >> 4;
    const int wm = w >> 1, wn = w & 1;
    const int mbase = blockIdx.y * 128;
    const int nbase = blockIdx.x * 128;

    const int srow = lane >> 3, schk = lane & 7;
    const bf16* gA = A + (size_t)(mbase + srow) * K + schk * 8;
    const bf16* gB1 = B1 + (size_t)(nbase + srow) * K + schk * 8;
    const bf16* gB3 = B3 + (size_t)(nbase + srow) * K + schk * 8;

    f32x4 acc1[4][4] = {};
    f32x4 acc3[4][4] = {};

    for (int k0 = 0; k0 < K; k0 += 64) {
        __syncthreads();
#pragma unroll
        for (int g = 0; g < 4; g++) {
            const int grp = w * 4 + g;
            __builtin_amdgcn_global_load_lds(
                (const AS1 void*)(gA + (size_t)(grp * 8) * K + k0),
                (AS3 void*)&As[grp * 8 * 64], 16, 0, 0);
            __builtin_amdgcn_global_load_lds(
                (const AS1 void*)(gB1 + (size_t)(grp * 8) * K + k0),
                (AS3 void*)&B1s[grp * 8 * 64], 16, 0, 0);
            __builtin_amdgcn_global_load_lds(
                (const AS1 void*)(gB3 + (size_t)(grp * 8) * K + k0),
                (AS3 void*)&B3s[grp * 8 * 64], 16, 0, 0);
        }
        __syncthreads();

#pragma unroll
        for (int kk = 0; kk < 2; kk++) {
            bf16x8 a[4], b1[4], b3[4];
#pragma unroll
            for (int i = 0; i < 4; i++)
                a[i] = *(const bf16x8*)&As[(wm * 64 + i * 16 + c) * 64 + kk * 32 + qd * 8];
#pragma unroll
            for (int j = 0; j < 4; j++) {
                b1[j] = *(const bf16x8*)&B1s[(wn * 64 + j * 16 + c) * 64 + kk * 32 + qd * 8];
                b3[j] = *(const bf16x8*)&B3s[(wn * 64 + j * 16 + c) * 64 + kk * 32 + qd * 8];
            }
#pragma unroll
            for (int i = 0; i < 4; i++)
#pragma unroll
                for (int j = 0; j < 4; j++) {
                    acc1[i][j] = __builtin_amdgcn_mfma_f32_16x16x32_bf16(a[i], b1[j], acc1[i][j], 0, 0, 0);
                    acc3[i][j] = __builtin_amdgcn_mfma_f32_16x16x32_bf16(a[i], b3[j], acc3[i][j], 0, 0, 0);
                }
        }
    }

#pragma unroll
    for (int i = 0; i < 4; i++) {
#pragma unroll
        for (int j = 0; j < 4; j++) {
            const int col = nbase + wn * 64 + j * 16 + c;
#pragma unroll
            for (int reg = 0; reg < 4; reg++) {
                const int row = mbase + wm * 64 + i * 16 + qd * 4 + reg;
                const float a1 = acc1[i][j][reg];
                const float h = (a1 / (1.0f + __expf(-a1))) * acc3[i][j][reg];
                out[(size_t)row * N + col] = (bf16)h;
            }
        }
    }
}

// ---------------------------------------------------------------------------
// Transpose a qkv section to [h][d][t].  Block (0,0) also zeroes the attn
// work-queue counters (fused zero_ctr).
// ---------------------------------------------------------------------------
#define CTR_STRIDE 16  // ints; 64 B per counter line
__global__ __launch_bounds__(256) void build_tr(const bf16* __restrict__ qkv,
                                                bf16* __restrict__ dst, int soff,
                                                int* __restrict__ ctrs) {
    if (blockIdx.x == 0 && blockIdx.y == 0 && threadIdx.x < 8 * CTR_STRIDE)
        ctrs[threadIdx.x] = 0;
    const int h = blockIdx.y;
    const int tb = blockIdx.x;
    __shared__ bf16 tile[64][65];
    const int tx = threadIdx.x & 63;
    const int ty = threadIdx.x >> 6;
    for (int rr = ty; rr < 64; rr += 4)
        tile[rr][tx] = qkv[(size_t)(tb * 64 + rr) * LD_QKV + soff + h * 64 + tx];
    __syncthreads();
    for (int rr = ty; rr < 64; rr += 4)
        dst[((size_t)h * 64 + rr) * T_SEQ + tb * 64 + tx] = tile[tx][rr];
}

// ---------------------------------------------------------------------------
// MFMA flash attention — round-8 body, verbatim (measured 100.6-101.5 us
// across five rounds).  Persistent blocks + 8 LPT work queues (whole tiles,
// qb descending) + scale-folded exp2 softmax + defer-max + serial
// reg-staging (reg 100.7 < gload_lds 117.4 < dbuf 151 us).
// ---------------------------------------------------------------------------
__global__ __launch_bounds__(256) void attn_mfma(const bf16* __restrict__ qkv,
                                                 const bf16* __restrict__ VT,
                                                 bf16* __restrict__ y,
                                                 int* __restrict__ ctrs) {
    __shared__ __align__(16) bf16r Ks[128][64];    // keys x d
    __shared__ __align__(16) bf16r VTs[64][128];   // d x keys
    __shared__ __align__(16) bf16r Ps[4][16][128]; // per-wave q x keys
    __shared__ int s_wi;

    const int tid  = threadIdx.x;
    const int w    = tid >> 6;
    const int lane = tid & 63;
    const int c    = lane & 15;
    const int qd   = lane >> 4;
    const int sw   = c & 7;            // xor swizzle key for frag reads
    const int qi   = blockIdx.x & 7;   // queue = presumed XCD
    int* ctr = ctrs + qi * CTR_STRIDE;

    while (true) {
        __syncthreads();               // LDS + s_wi safe to reuse
        if (tid == 0) s_wi = atomicAdd(ctr, 1);
        __syncthreads();
        const int j = s_wi;
        if (j >= 128) break;           // queue drained (uniform exit)

        const int h    = qi + 8 * (j & 1);      // heads {qi, qi+8}
        const int qb   = 63 - (j >> 1);         // largest-first (LPT)
        const int qrow = qb * 64 + w * 16 + c;

        // Q B-frags: lane holds Q[qrow][ks*32 + qd*8 + jj]  (pre-scaled by SCL)
        bf16x8 qf[2];
        {
            const bf16* qp = qkv + (size_t)qrow * LD_QKV + h * 64;
            qf[0] = *(const bf16x8*)(qp + qd * 8);
            qf[1] = *(const bf16x8*)(qp + 32 + qd * 8);
        }

        f32x4 O[4] = {};               // O^T: D[row=d=dt*16+qd*4+r][col=q=c]
        float m_i = -1e30f, l_i = 0.f; // m_i in log2 domain
        const int nkb = (qb >> 1) + 1; // 128-key chunks

        for (int kb = 0; kb < nkb; kb++) {
            __syncthreads();           // prior iteration's LDS reads done
#pragma unroll
            for (int ii = 0; ii < 4; ii++) {
                const int i = ii * 256 + tid;
                const int kr = i >> 3, ch = i & 7;    // K: 128 rows x 8 chunks
                *(bf16x8*)&Ks[kr][(ch ^ (kr & 7)) * 8] =
                    *(const bf16x8*)(qkv + (size_t)(kb * 128 + kr) * LD_QKV + C_DIM + h * 64 + ch * 8);
                const int vr = i >> 4, vch = i & 15;  // VT: 64 rows x 16 chunks
                *(bf16x8*)&VTs[vr][(vch ^ (vr & 7)) * 8] =
                    *(const bf16x8*)(VT + ((size_t)h * 64 + vr) * T_SEQ + kb * 128 + vch * 8);
            }
            __syncthreads();

            // ---- S^T = K Q^T : rows = keys (kt*16+qd*4+r), cols = q (c) ----
            f32x4 ST[8];
#pragma unroll
            for (int kt = 0; kt < 8; kt++) {
                f32x4 z = {};
#pragma unroll
                for (int ks = 0; ks < 2; ks++) {
                    bf16x8 kf = *(const bf16x8*)&Ks[kt * 16 + c][((ks * 4 + qd) ^ sw) * 8];
                    z = __builtin_amdgcn_mfma_f32_16x16x32_bf16(kf, qf[ks], z, 0, 0, 0);
                }
                ST[kt] = z;
            }

            // ---- causal mask on the diagonal chunk only ----
            if (kb == nkb - 1) {
#pragma unroll
                for (int kt = 0; kt < 8; kt++)
#pragma unroll
                    for (int r = 0; r < 4; r++)
                        if (kb * 128 + kt * 16 + qd * 4 + r > qrow) ST[kt][r] = -1e30f;
            }

            // ---- online softmax (exp2 domain), per-lane scalar stats ----
            float mb = -1e30f;
#pragma unroll
            for (int kt = 0; kt < 8; kt++)
#pragma unroll
                for (int r = 0; r < 4; r++) mb = fmaxf(mb, ST[kt][r]);
            mb = fmaxf(mb, __shfl_xor(mb, 16));
            mb = fmaxf(mb, __shfl_xor(mb, 32));

            bf16x4 pv[8];
            float rs = 0.f;
            if (__all(mb - m_i <= 8.0f)) {
                // defer-max: keep m_i, skip alpha-rescale; P bounded by 2^8
#pragma unroll
                for (int kt = 0; kt < 8; kt++)
#pragma unroll
                    for (int r = 0; r < 4; r++) {
                        const float p = exp2f(ST[kt][r] - m_i);
                        pv[kt][r] = (bf16r)p;
                        rs += p;
                    }
                rs += __shfl_xor(rs, 16);
                rs += __shfl_xor(rs, 32);
                l_i += rs;
            } else {
                const float mnew = fmaxf(m_i, mb);
                const float alpha = exp2f(m_i - mnew);
#pragma unroll
                for (int kt = 0; kt < 8; kt++)
#pragma unroll
                    for (int r = 0; r < 4; r++) {
                        const float p = exp2f(ST[kt][r] - mnew);
                        pv[kt][r] = (bf16r)p;
                        rs += p;
                    }
                rs += __shfl_xor(rs, 16);
                rs += __shfl_xor(rs, 32);
                l_i = l_i * alpha + rs;
                m_i = mnew;
#pragma unroll
                for (int dt = 0; dt < 4; dt++)
#pragma unroll
                    for (int r = 0; r < 4; r++) O[dt][r] *= alpha;
            }

            // ---- P^T -> Ps[q][key] via 8B vector writes (wave-private) ----
#pragma unroll
            for (int kt = 0; kt < 8; kt++) {
                const int phys = (kt * 2 + (qd >> 1)) ^ sw;  // 16B-chunk swizzle
                *(bf16x4*)&Ps[w][c][phys * 8 + (qd & 1) * 4] = pv[kt];
            }

            // ---- O^T += VT P^T (16x16x32) ----
#pragma unroll
            for (int ks = 0; ks < 4; ks++) {
                bf16x8 pf = *(const bf16x8*)&Ps[w][c][((ks * 4 + qd) ^ sw) * 8];
#pragma unroll
                for (int dt = 0; dt < 4; dt++) {
                    bf16x8 vf = *(const bf16x8*)&VTs[dt * 16 + c][((ks * 4 + qd) ^ sw) * 8];
                    O[dt] = __builtin_amdgcn_mfma_f32_16x16x32_bf16(vf, pf, O[dt], 0, 0, 0);
                }
            }
        }

        // ---- epilogue: y[qrow][h*64 + d], 8B vector stores ----
        const float inv_l = 1.0f / l_i;
#pragma unroll
        for (int dt = 0; dt < 4; dt++) {
            bf16x4 ov;
#pragma unroll
            for (int r = 0; r < 4; r++) ov[r] = (bf16r)(O[dt][r] * inv_l);
            *(bf16x4*)(y + (size_t)qrow * C_DIM + h * 64 + dt * 16 + qd * 4) = ov;
        }
    }
}

// ---------------------------------------------------------------------------
// launch.  Inputs f32, output f32.  ws peak = 56 MiB.
//
// Region timeline (stream-ordered, audited):
//   0..6   cwA  (live until qkv gemm) -> rms2 [0..8] after rmsnorm_res
//   6..8   cwP  (live until proj)
//   8..16  rms1/ctrs (ctrs written by build_tr after qkv gemm)
//          -> P0 [8..24] after attn -> w1h [8..16] after rmsnorm_res
//          -> w2h [8..16] after w13 gemm
//   16..40 qkv (live until attn) -> P0 tail/P1 [24..40] -> w3h [16..24]
//   40..48 VT  (live until attn) -> h1
//   48..56 y   (live until proj) -> h1
//   24..56 h1 [4096][4096] bf16 after rmsnorm_res+cvt_w13.
// ---------------------------------------------------------------------------
extern "C" void kernel_launch(void* const* d_in, const int* in_sizes, int n_in,
                              void* d_out, int out_size, void* d_ws, size_t ws_size,
                              hipStream_t stream) {
    const float* x        = (const float*)d_in[0];
    const float* attn_w   = (const float*)d_in[1];
    const float* ffn_w    = (const float*)d_in[2];
    const float* c_attn_w = (const float*)d_in[3];
    const float* c_proj_w = (const float*)d_in[4];
    const float* w1       = (const float*)d_in[5];
    const float* w2       = (const float*)d_in[6];
    const float* w3       = (const float*)d_in[7];
    float* xmid = (float*)d_out;

    char* ws = (char*)d_ws;
    bf16* cwA  = (bf16*)(ws);            // 0..6   (cwA||cwP contiguous)
    bf16* cwP  = (bf16*)(ws + MB(6));    // 6..8
    bf16* rms1 = (bf16*)(ws + MB(8));    // 8..16
    bf16* qkv  = (bf16*)(ws + MB(16));   // 16..40
    bf16* VT   = (bf16*)(ws + MB(40));   // 40..48
    bf16* y    = (bf16*)(ws + MB(48));   // 48..56
    int*  ctrs = (int*)(ws + MB(8));     // over rms1 (dead after qkv gemm)
    float* P0  = (float*)(ws + MB(8));   // proj partials: 8..24 (z=0), 24..40 (z=1)
    float* P1  = (float*)(ws + MB(24));
    bf16* rms2 = (bf16*)(ws);            // 0..8 (over cwA/cwP, after rmsnorm_res)
    bf16* w1h  = (bf16*)(ws + MB(8));    // 8..16 (over P0, after rmsnorm_res)
    bf16* w3h  = (bf16*)(ws + MB(16));   // 16..24 (over P0 tail)
    bf16* w2h  = (bf16*)(ws + MB(8));    // 8..16 (over w1h, after w13 gemm)
    bf16* h1   = (bf16*)(ws + MB(24));   // 24..56 (over P1/VT/y)

    // 1. attention weights -> bf16 (fused; Q-proj rows x SCL)
    cvt_attn<<<512, 256, 0, stream>>>(c_attn_w, c_proj_w, (ushort4*)cwA);
    // 2. rms1 = rmsnorm(x, attn_norm_w)
    rmsnorm_k<<<T_SEQ, 256, 0, stream>>>(x, attn_w, rms1);
    // 3. qkv = rms1 @ c_attn^T   [4096, 3072]
    gemm128<0, 0><<<dim3(24, 32), 256, 0, stream>>>(rms1, C_DIM, cwA, C_DIM, nullptr, qkv, 3072, 1024);
    // 4. VT (+ ctr zero) + persistent-block flash attention
    build_tr<<<dim3(64, 16), 256, 0, stream>>>(qkv, VT, 2 * C_DIM, ctrs);
    attn_mfma<<<768, 256, 0, stream>>>(qkv, VT, y, ctrs);
    // 5. proj partials: P[z] = y @ c_proj^T (slice z), plain f32 stores
    //    (replaces copy_f32 prefill + atomicAdd RMW)
    gemm128<5, 1><<<dim3(8, 32, 2), 256, 0, stream>>>(y, C_DIM, cwP, C_DIM, nullptr, P0, 1024, 512);
    // 6. fused residual join: xmid = x+P0+P1 (f32), rms2 = rmsnorm(xmid)*w
    rmsnorm_res<<<T_SEQ, 256, 0, stream>>>(x, P0, P1, ffn_w, xmid, rms2);
    // 7. FFN weight converts (P0/P1 regions now dead)
    cvt_w13<<<512, 256, 0, stream>>>(w1, w3, (ushort4*)w1h, (ushort4*)w3h, 4096 * 1024 / 4);
    // 8. h1 = silu(rms2@w1^T)*(rms2@w3^T), fused dual-acc, single pass
    gemm_w13<<<dim3(32, 32), 256, 0, stream>>>(rms2, w1h, w3h, h1, 4096, 1024);
    // 9. xmid += h1 @ w2^T   (full K=4096, split-K=4 atomic; 1024 blocks)
    cvt_w<<<512, 256, 0, stream>>>(w2, 0, (ushort4*)w2h, 1024 * 4096 / 4);
    gemm128<4, 1><<<dim3(8, 32, 4), 256, 0, stream>>>(h1, 4096, w2h, 4096, nullptr, xmid, 1024, 1024);
}